// Round 17
// baseline (112.574 us; speedup 1.0000x reference)
//
#include <hip/hip_runtime.h>

#define NN 100000
#define DD 384
#define CC 8

typedef unsigned int uint;
typedef _Float16 half8 __attribute__((ext_vector_type(8)));
typedef float floatx4 __attribute__((ext_vector_type(4)));

__device__ __forceinline__ constexpr int TIDX(int i, int j) { return i * (i + 1) / 2 + j; }

__device__ __forceinline__ uint pkh2(float a, float b) {
  return __builtin_bit_cast(uint, __builtin_amdgcn_cvt_pkrtz(a, b));
}

// B-fragment pre-pack (verified R8-R16). B[d][col]: col 0..35 = lower-tri of
// Sigmaw[d]+w w^T, 36..43 = wbar, 44..47 = 0.  mfma_f32_16x16x32_f16
// B-operand: lane holds 8 f16 at col = ct*16+(lane&15), k(j) = kt*32+(lane>>4)*8+j.
__global__ __launch_bounds__(64) void vbpca_prep(
    const float* __restrict__ wbar, const float* __restrict__ Sigmaw,
    uint4* __restrict__ bfrag) {
  const int l = threadIdx.x;
  const int kt = blockIdx.x;  // 0..11
  const int kgrp = l >> 4;
#pragma unroll
  for (int ct = 0; ct < 3; ++ct) {
    const int col = ct * 16 + (l & 15);
    int ii = 0;
#pragma unroll
    for (int t = 0; t < 7; ++t) {
      if ((ii + 1) * (ii + 2) / 2 <= col && ii < 7) ++ii;
    }
    const int jj = col - ii * (ii + 1) / 2;
    float v[8];
#pragma unroll
    for (int j = 0; j < 8; ++j) {
      const int d = kt * 32 + kgrp * 8 + j;
      float val;
      if (col < 36) {
        val = Sigmaw[(size_t)d * 64 + ii * 8 + jj] + wbar[d * 8 + ii] * wbar[d * 8 + jj];
      } else if (col < 44) {
        val = wbar[d * 8 + (col - 36)];
      } else {
        val = 0.f;
      }
      v[j] = val;
    }
    uint4 u;
    u.x = pkh2(v[0], v[1]); u.y = pkh2(v[2], v[3]);
    u.z = pkh2(v[4], v[5]); u.w = pkh2(v[6], v[7]);
    bfrag[(kt * 3 + ct) * 64 + l] = u;
  }
}

// KERNEL A: pure streaming MFMA, no epilogue. 4 waves/block, each wave owns
// ONE M-tile (8 orig rows). Gather-direct fragments (R15, verified), 36 MFMA,
// then predicated raw-C store to ws intermediate [row][48] (0..35 Gram,
// 36..43 proj). LDS = mbar only (1.5KB) -> up to 8 blocks/CU.
__global__ __launch_bounds__(256, 8) void vbpca_mfma(
    const float* __restrict__ Y, const int* __restrict__ O,
    const uint4* __restrict__ bfrag, const float* __restrict__ mbar,
    float* __restrict__ cws) {
  __shared__ float mbar_l[DD];
  const int tid = threadIdx.x;
  const int wu = __builtin_amdgcn_readfirstlane((int)(tid >> 6));
  const int l = tid & 63;

  for (int i = tid; i < DD; i += 256) mbar_l[i] = mbar[i];
  __syncthreads();

  const int R0 = blockIdx.x * 32 + wu * 8;  // 3125*32 = 100000 exactly, no tail
  const int gr = R0 + ((l & 15) >> 1);
  const float tsel = (float)(l & 1);
  const float osel = 1.f - tsel;
  const int kgo = (l >> 4) * 8;

  const float* __restrict__ Yr = Y + (size_t)gr * DD;
  const int* __restrict__ Or = O + (size_t)gr * DD;

  floatx4 acc[3];
#pragma unroll
  for (int j = 0; j < 3; ++j) acc[j] = (floatx4){0.f, 0.f, 0.f, 0.f};

  uint4 bf0 = bfrag[0 * 64 + l];
  uint4 bf1 = bfrag[1 * 64 + l];
  uint4 bf2 = bfrag[2 * 64 + l];
#pragma unroll
  for (int kt = 0; kt < 12; ++kt) {
    const int kb = kt * 32 + kgo;
    const float4 ylo = *reinterpret_cast<const float4*>(Yr + kb);
    const float4 yhi = *reinterpret_cast<const float4*>(Yr + kb + 4);
    const int4 olo = *reinterpret_cast<const int4*>(Or + kb);
    const int4 ohi = *reinterpret_cast<const int4*>(Or + kb + 4);
    const float4 mlo = *reinterpret_cast<const float4*>(mbar_l + kb);
    const float4 mhi = *reinterpret_cast<const float4*>(mbar_l + kb + 4);
    const float v0 = (float)olo.x * fmaf(tsel, ylo.x - mlo.x, osel);
    const float v1 = (float)olo.y * fmaf(tsel, ylo.y - mlo.y, osel);
    const float v2 = (float)olo.z * fmaf(tsel, ylo.z - mlo.z, osel);
    const float v3 = (float)olo.w * fmaf(tsel, ylo.w - mlo.w, osel);
    const float v4 = (float)ohi.x * fmaf(tsel, yhi.x - mhi.x, osel);
    const float v5 = (float)ohi.y * fmaf(tsel, yhi.y - mhi.y, osel);
    const float v6 = (float)ohi.z * fmaf(tsel, yhi.z - mhi.z, osel);
    const float v7 = (float)ohi.w * fmaf(tsel, yhi.w - mhi.w, osel);
    uint4 fu;
    fu.x = pkh2(v0, v1); fu.y = pkh2(v2, v3);
    fu.z = pkh2(v4, v5); fu.w = pkh2(v6, v7);
    const half8 av = __builtin_bit_cast(half8, fu);
    uint4 nb0, nb1, nb2;
    if (kt < 11) {
      nb0 = bfrag[((kt + 1) * 3 + 0) * 64 + l];
      nb1 = bfrag[((kt + 1) * 3 + 1) * 64 + l];
      nb2 = bfrag[((kt + 1) * 3 + 2) * 64 + l];
    }
    acc[0] = __builtin_amdgcn_mfma_f32_16x16x32_f16(
        av, __builtin_bit_cast(half8, bf0), acc[0], 0, 0, 0);
    acc[1] = __builtin_amdgcn_mfma_f32_16x16x32_f16(
        av, __builtin_bit_cast(half8, bf1), acc[1], 0, 0, 0);
    acc[2] = __builtin_amdgcn_mfma_f32_16x16x32_f16(
        av, __builtin_bit_cast(half8, bf2), acc[2], 0, 0, 0);
    bf0 = nb0; bf1 = nb1; bf2 = nb2;
  }

  // C/D layout: col = l&15, C-row m = (l>>4)*4 + reg. m even -> Gram row
  // (cols<36), m odd -> proj row (cols 36..43). Orig row = R0 + (m>>1).
  const int lm = l & 15;
  const int g2 = (l >> 4) * 2;
#pragma unroll
  for (int reg = 0; reg < 4; ++reg) {
    float* wr = cws + (size_t)(R0 + g2 + (reg >> 1)) * 48;
    if ((reg & 1) == 0) {
      wr[0 * 16 + lm] = acc[0][reg];
      wr[1 * 16 + lm] = acc[1][reg];
      if (lm < 4) wr[2 * 16 + lm] = acc[2][reg];
    } else {
      if (lm >= 4 && lm < 12) wr[2 * 16 + lm] = acc[2][reg];
    }
  }
}

// KERNEL B: solve + output. 64 rows/block: coalesced-stage [64][48] records
// into LDS, 64 solver threads run the verified Cholesky chain, staged
// coalesced copy-out (verified R9-R16 epilogue tail).
__global__ __launch_bounds__(256) void vbpca_solve(
    const float* __restrict__ cws, const float* __restrict__ vyp,
    float* __restrict__ out) {
  __shared__ float stg[64 * 48];    // 12288 B
  __shared__ float sigst[64 * 65];  // 16640 B
  __shared__ float xbst[64 * 9];    // 2304 B

  const int tid = threadIdx.x;
  const int base = blockIdx.x * 64;

  float4* stg4 = reinterpret_cast<float4*>(stg);
  const float4* cws4 = reinterpret_cast<const float4*>(cws);
  for (int f = tid; f < 768; f += 256) {
    int rr = base + f / 12;
    rr = rr < NN ? rr : NN - 1;
    stg4[f] = cws4[(size_t)rr * 12 + (f % 12)];
  }
  __syncthreads();

  if (tid < 64) {
    const int row = tid;
    const float vy = *vyp;
    float a[36], pr[CC];
#pragma unroll
    for (int k = 0; k < 36; ++k) a[k] = stg[row * 48 + k];
#pragma unroll
    for (int j = 0; j < CC; ++j) pr[j] = stg[row * 48 + 36 + j];

    float L[36];
#pragma unroll
    for (int j = 0; j < CC; ++j) {
      float s = a[TIDX(j, j)] + vy;
#pragma unroll
      for (int k = 0; k < CC; ++k) {
        if (k < j) s -= L[TIDX(j, k)] * L[TIDX(j, k)];
      }
      const float dj = sqrtf(s);
      L[TIDX(j, j)] = dj;
      const float invdj = 1.0f / dj;
#pragma unroll
      for (int i = j + 1; i < CC; ++i) {
        float tt = a[TIDX(i, j)];
#pragma unroll
        for (int k = 0; k < CC; ++k) {
          if (k < j) tt -= L[TIDX(i, k)] * L[TIDX(j, k)];
        }
        L[TIDX(i, j)] = tt * invdj;
      }
    }

    float invd[CC];
#pragma unroll
    for (int i = 0; i < CC; ++i) invd[i] = 1.0f / L[TIDX(i, i)];
    float Li[36];
#pragma unroll
    for (int j = 0; j < CC; ++j) {
      Li[TIDX(j, j)] = invd[j];
#pragma unroll
      for (int i = j + 1; i < CC; ++i) {
        float s = 0.f;
#pragma unroll
        for (int k = 0; k < CC; ++k) {
          if (k >= j && k < i) s += L[TIDX(i, k)] * Li[TIDX(k, j)];
        }
        Li[TIDX(i, j)] = -s * invd[i];
      }
    }

    float sig[36];
#pragma unroll
    for (int i = 0; i < CC; ++i) {
#pragma unroll
      for (int j = 0; j <= i; ++j) {
        float s = 0.f;
#pragma unroll
        for (int k = 0; k < CC; ++k) {
          if (k >= i) s += Li[TIDX(k, i)] * Li[TIDX(k, j)];
        }
        sig[TIDX(i, j)] = vy * s;
      }
    }

    float uvec[CC];
#pragma unroll
    for (int i = 0; i < CC; ++i) {
      float s = 0.f;
#pragma unroll
      for (int j = 0; j < CC; ++j) {
        if (j <= i) s += Li[TIDX(i, j)] * pr[j];
      }
      uvec[i] = s;
    }
#pragma unroll
    for (int ll = 0; ll < CC; ++ll) {
      float s = 0.f;
#pragma unroll
      for (int i = 0; i < CC; ++i) {
        if (i >= ll) s += Li[TIDX(i, ll)] * uvec[i];
      }
      xbst[row * 9 + ll] = s;
    }
#pragma unroll
    for (int i = 0; i < CC; ++i) {
#pragma unroll
      for (int j = 0; j < CC; ++j) {
        sigst[row * 65 + i * 8 + j] = (j <= i) ? sig[TIDX(i, j)] : sig[TIDX(j, i)];
      }
    }
  }
  __syncthreads();

  const int valid = (NN - base < 64) ? (NN - base) : 64;
  float* __restrict__ sig_out = out + (size_t)NN * CC + (size_t)base * 64;
  for (int f = tid; f < valid * 64; f += 256) {
    sig_out[f] = sigst[(f >> 6) * 65 + (f & 63)];
  }
  float* __restrict__ xb_out = out + (size_t)base * CC;
  for (int f = tid; f < valid * 8; f += 256) {
    xb_out[f] = xbst[(f >> 3) * 9 + (f & 7)];
  }
}

extern "C" void kernel_launch(void* const* d_in, const int* in_sizes, int n_in,
                              void* d_out, int out_size, void* d_ws, size_t ws_size,
                              hipStream_t stream) {
  const float* Y = (const float*)d_in[0];
  const int* O = (const int*)d_in[1];
  const float* mbar = (const float*)d_in[2];
  const float* wbar = (const float*)d_in[3];
  const float* Sigmaw = (const float*)d_in[4];
  const float* vyp = (const float*)d_in[5];
  float* out = (float*)d_out;
  uint4* bfrag = (uint4*)d_ws;                       // 36864 B
  float* cws = (float*)((char*)d_ws + 36864);        // 100000*48*4 = 19.2 MB

  vbpca_prep<<<12, 64, 0, stream>>>(wbar, Sigmaw, bfrag);
  vbpca_mfma<<<NN / 32, 256, 0, stream>>>(Y, O, bfrag, mbar, cws);
  vbpca_solve<<<(NN + 63) / 64, 256, 0, stream>>>(cws, vyp, out);
}